// Round 7
// baseline (111.983 us; speedup 1.0000x reference)
//
#include <hip/hip_runtime.h>

// Grouped GEMM a[16384,512] x b[8][512,512] (fp32, groups of 2048 rows) -> fp32.
// R7 = R2 (best, 106.8) + pre-transposed bf16 B ONLY.
//   P1: B [g][k][n] fp32 -> bf16 [g][n][k]  (12.6 MB traffic, ~2us; verified R3)
//   P2: R2's K-loop, but B staging now mirrors A staging (contiguous-k bf16x8
//       loads, no in-register transpose, b128 ds_writes): ~25% fewer VMEM
//       instrs, ~half the staging VALU, -67 MB L3 read service.
// Kept from R2: 128x128 tile, BK=64, dbuf LDS, single barrier/iter, register
// prefetch issued AFTER the barrier, linear tm/tn (XCD swizzle was neutral, R6).
// R5 lesson kept: fragments always come from LDS.

#define KDIM 512
#define NDIM 512
#define BM 128
#define BN 128
#define BK 64
#define LDSTRIDE 72   // 64 + 8 bf16 pad (144 B rows)

typedef __bf16 bf16x8 __attribute__((ext_vector_type(8)));
typedef __bf16 bf16x4 __attribute__((ext_vector_type(4)));
typedef float  f32x4  __attribute__((ext_vector_type(4)));

// ---------------- P1: B [g][k][n] fp32 -> bf16 [g][n][k] (verified R3) ----
#define TSTRIDE 68
__global__ __launch_bounds__(256)
void cvtB_kernel(const float* __restrict__ B, __bf16* __restrict__ Bt) {
    __shared__ __bf16 tile[64 * TSTRIDE];
    const int bid = blockIdx.x;
    const int g  = bid >> 6;
    const int kt = (bid >> 3) & 7;
    const int nt = bid & 7;
    const int k0 = kt * 64, n0 = nt * 64;
    const int t = threadIdx.x;

    const int rk = (t >> 4) * 4;
    const int rn = (t & 15) * 4;
#pragma unroll
    for (int dk = 0; dk < 4; ++dk) {
        f32x4 v = *(const f32x4*)(B + (size_t)(g * KDIM + k0 + rk + dk) * NDIM + n0 + rn);
        bf16x4 w;
        w[0] = (__bf16)v[0]; w[1] = (__bf16)v[1]; w[2] = (__bf16)v[2]; w[3] = (__bf16)v[3];
        *(bf16x4*)&tile[(rk + dk) * TSTRIDE + rn] = w;
    }
    __syncthreads();
    const int on = t >> 2;
    const int kc = (t & 3) * 16;
    bf16x8 o0, o1;
#pragma unroll
    for (int j = 0; j < 8; ++j) o0[j] = tile[(kc + j) * TSTRIDE + on];
#pragma unroll
    for (int j = 0; j < 8; ++j) o1[j] = tile[(kc + 8 + j) * TSTRIDE + on];
    __bf16* dst = Bt + (size_t)(g * NDIM + n0 + on) * KDIM + k0 + kc;
    *(bf16x8*)dst = o0;
    *(bf16x8*)(dst + 8) = o1;
}

// ---------------- P2: R2 GEMM with bf16 [n][k] B source ----------------
__global__ __launch_bounds__(256, 2)
void grouped_gemm_kernel(const float* __restrict__ A,
                         const __bf16* __restrict__ Bt,
                         const int*   __restrict__ glist,
                         float*       __restrict__ C,
                         int M, int G)
{
    __shared__ __bf16 As[2][BM * LDSTRIDE];
    __shared__ __bf16 Bs[2][BN * LDSTRIDE];

    const int nTilesN = NDIM / BN;             // 4
    const int tm = blockIdx.x / nTilesN;
    const int tn = blockIdx.x % nTilesN;
    const int row0 = tm * BM;
    const int col0 = tn * BN;

    int gid = 0;
    for (int g = 0; g < G; ++g) gid += (glist[g] <= row0) ? 1 : 0;
    const __bf16* Bg = Bt + (size_t)gid * NDIM * KDIM;

    const int t    = threadIdx.x;
    const int lane = t & 63;
    const int wave = t >> 6;
    const int wm   = wave >> 1;
    const int wn   = wave & 1;
    const int lm   = lane & 15;
    const int quad = lane >> 4;

    // A and B staging (identical shape): 8/16-B segment along k x 4 rows (stride 32)
    const int s_seg = t & 7;      // k segment: 8 elems
    const int s_row = t >> 3;     // 0..31

    const float*  aptr = A  + (size_t)(row0 + s_row) * KDIM + s_seg * 8;
    const __bf16* bptr = Bg + (size_t)(col0 + s_row) * KDIM + s_seg * 8;

    f32x4  ra[4][2];
    bf16x8 rbv[4];

    // ---- prologue: K-tile 0 into registers ----
#pragma unroll
    for (int s = 0; s < 4; ++s) {
        const float* p = aptr + (size_t)(s * 32) * KDIM;
        ra[s][0] = *(const f32x4*)p;
        ra[s][1] = *(const f32x4*)(p + 4);
        rbv[s]   = *(const bf16x8*)(bptr + (size_t)(s * 32) * KDIM);
    }

    f32x4 acc[4][4];
#pragma unroll
    for (int ii = 0; ii < 4; ++ii)
#pragma unroll
        for (int j = 0; j < 4; ++j)
            acc[ii][j] = (f32x4){0.f, 0.f, 0.f, 0.f};

    const int NITER = KDIM / BK;               // 8
    for (int it = 0; it < NITER; ++it) {
        __bf16* as = As[it & 1];
        __bf16* bs = Bs[it & 1];

        // ---- cvt + stage A (vmcnt wait lands here) ----
#pragma unroll
        for (int s = 0; s < 4; ++s) {
            const int r = s_row + s * 32;
            bf16x8 w;
            w[0] = (__bf16)ra[s][0][0]; w[1] = (__bf16)ra[s][0][1];
            w[2] = (__bf16)ra[s][0][2]; w[3] = (__bf16)ra[s][0][3];
            w[4] = (__bf16)ra[s][1][0]; w[5] = (__bf16)ra[s][1][1];
            w[6] = (__bf16)ra[s][1][2]; w[7] = (__bf16)ra[s][1][3];
            *(bf16x8*)&as[r * LDSTRIDE + s_seg * 8] = w;
        }
        // ---- stage B: already bf16 [n][k]; apply frag-read XOR swizzle ----
#pragma unroll
        for (int s = 0; s < 4; ++s) {
            const int n = s_row + s * 32;
            const int phys = s_seg ^ ((n >> 3) & 7);
            *(bf16x8*)&bs[n * LDSTRIDE + phys * 8] = rbv[s];
        }

        __syncthreads();

        // ---- prefetch next K-tile AFTER the barrier ----
        if (it < NITER - 1) {
            const int kb = (it + 1) * BK;
#pragma unroll
            for (int s = 0; s < 4; ++s) {
                const float* p = aptr + (size_t)(s * 32) * KDIM + kb;
                ra[s][0] = *(const f32x4*)p;
                ra[s][1] = *(const f32x4*)(p + 4);
                rbv[s]   = *(const bf16x8*)(bptr + (size_t)(s * 32) * KDIM + kb);
            }
        }

        // ---- fragments + 32 MFMAs ----
#pragma unroll
        for (int ks = 0; ks < 2; ++ks) {
            const int g16 = ks * 4 + quad;
            bf16x8 af[4], bfr[4];
#pragma unroll
            for (int ii = 0; ii < 4; ++ii) {
                const int m = wm * 64 + ii * 16 + lm;
                af[ii] = *(const bf16x8*)&as[m * LDSTRIDE + g16 * 8];
            }
#pragma unroll
            for (int j = 0; j < 4; ++j) {
                const int n = wn * 64 + j * 16 + lm;
                const int phys = g16 ^ ((n >> 3) & 7);
                bfr[j] = *(const bf16x8*)&bs[n * LDSTRIDE + phys * 8];
            }
#pragma unroll
            for (int ii = 0; ii < 4; ++ii)
#pragma unroll
                for (int j = 0; j < 4; ++j)
                    acc[ii][j] = __builtin_amdgcn_mfma_f32_16x16x32_bf16(
                        af[ii], bfr[j], acc[ii][j], 0, 0, 0);
        }
    }

    // ---- epilogue: C/D layout col=lane&15, row=quad*4+reg ----
#pragma unroll
    for (int ii = 0; ii < 4; ++ii) {
        const int gr0 = row0 + wm * 64 + ii * 16 + quad * 4;
#pragma unroll
        for (int j = 0; j < 4; ++j) {
            const int gc = col0 + wn * 64 + j * 16 + lm;
#pragma unroll
            for (int r = 0; r < 4; ++r)
                C[(size_t)(gr0 + r) * NDIM + gc] = acc[ii][j][r];
        }
    }
}

extern "C" void kernel_launch(void* const* d_in, const int* in_sizes, int n_in,
                              void* d_out, int out_size, void* d_ws, size_t ws_size,
                              hipStream_t stream) {
    const float* a  = (const float*)d_in[0];
    const float* bw = (const float*)d_in[1];
    const int*   gl = (const int*)d_in[2];
    float* out = (float*)d_out;

    const int M = in_sizes[0] / KDIM;          // 16384
    const int G = in_sizes[2];                 // 8

    __bf16* Bt = (__bf16*)d_ws;                // G*N*K bf16 = 4.2 MB

    cvtB_kernel<<<G * 64, 256, 0, stream>>>(bw, Bt);
    grouped_gemm_kernel<<<(M / BM) * (NDIM / BN), 256, 0, stream>>>(a, Bt, gl, out, M, G);
}